// Round 4
// baseline (718.803 us; speedup 1.0000x reference)
//
#include <hip/hip_runtime.h>

// LIF neuron: v_t = ALPHA*v_{t-1} + (x_t . w) - V_TH*z_{t-1}; z_t = 1[v_t > V_TH]
// x: [B=128, T=1000, N=1024] fp32, w: [N] fp32.
// Out: v_seq [B,T] ++ z_seq [B,T], flat fp32.
//
// Harness floor (R2/R3 post-mortem): dur_us includes ~495 us of per-iter
// restore (2 GB ws 0xAA poison ~327 us + 524 MB d_in restore ~165 us).
// Controllable kernel floor: x-read 524 MB / 6.3 TB/s ~= 83 us + ~10 us scan.
//
// R3 lesson: nontemporal loads + 4-rows/wave pipelining made dot ~60 us
// SLOWER than the simple 1-row/wave R1 version (NT lowers stream BW; extra
// VGPRs cut resident waves). This kernel is latency-hiding-bound, not
// issue-bound -> maximize wave count, keep VGPRs small, plain loads.

#define ALPHA 0.995f
#define V_TH 2.0f

constexpr int B = 128;
constexpr int T = 1000;
constexpr int N = 1024;

typedef float f32x4 __attribute__((ext_vector_type(4)));

// ---------------------------------------------------------------------------
// Kernel 1: drive_t[t*B + b] = dot(x[row,:], w), row = b*T + t.
// One wave per row (128k waves, ~8/SIMD resident, deep dispatch queue).
// 4 coalesced float4 loads in flight per wave; w re-read per wave is an
// L1 hit (4 KB, hot). fp64 accumulation: drive is ~exact, so spike-flip
// risk vs the np fp32 reference is minimized (a flip costs absmax >= 1.0
// vs threshold 0.785). launch_bounds(256,8) caps VGPRs at 64 (need ~50).
// ---------------------------------------------------------------------------
__global__ __launch_bounds__(256, 8) void lif_dot_kernel(
    const float* __restrict__ x, const float* __restrict__ w,
    float* __restrict__ drive_t) {
    const int lane = threadIdx.x & 63;
    const int row = blockIdx.x * 4 + (threadIdx.x >> 6);   // b*T + t, 0..127999
    const float* xr = x + (long long)row * N + lane * 4;
    const float* wp = w + lane * 4;

    // 8 loads issued before any dependent use (4 KB x + 4 KB w in flight)
    const f32x4 a0 = *(const f32x4*)(xr);
    const f32x4 a1 = *(const f32x4*)(xr + 256);
    const f32x4 a2 = *(const f32x4*)(xr + 512);
    const f32x4 a3 = *(const f32x4*)(xr + 768);
    const f32x4 w0 = *(const f32x4*)(wp);
    const f32x4 w1 = *(const f32x4*)(wp + 256);
    const f32x4 w2 = *(const f32x4*)(wp + 512);
    const f32x4 w3 = *(const f32x4*)(wp + 768);

    // 4 independent 4-deep fp64 chains
    double s0 = (double)a0.x*w0.x + (double)a0.y*w0.y + (double)a0.z*w0.z + (double)a0.w*w0.w;
    double s1 = (double)a1.x*w1.x + (double)a1.y*w1.y + (double)a1.z*w1.z + (double)a1.w*w1.w;
    double s2 = (double)a2.x*w2.x + (double)a2.y*w2.y + (double)a2.z*w2.z + (double)a2.w*w2.w;
    double s3 = (double)a3.x*w3.x + (double)a3.y*w3.y + (double)a3.z*w3.z + (double)a3.w*w3.w;
    double acc = (s0 + s1) + (s2 + s3);

    // wave64 butterfly reduction
#pragma unroll
    for (int off = 32; off >= 1; off >>= 1)
        acc += __shfl_down(acc, off);

    if (lane == 0) {
        const int b = row / T;
        const int t = row - b * T;
        drive_t[t * B + b] = (float)acc;   // [T,B] -> coalesced scan reads
    }
}

// ---------------------------------------------------------------------------
// Kernel 2: sequential LIF scan (unchanged from R3 — measured ~10 us).
// ONE block x 512 threads, tiles of 64 timesteps: coalesced float4 tile
// load -> 128 scan threads run recurrence into stride-65 LDS -> all 512
// threads store v/z tiles as aligned float4.
// ---------------------------------------------------------------------------
__global__ __launch_bounds__(512) void lif_scan_kernel(
    const float* __restrict__ drive_t, float* __restrict__ out) {
    __shared__ float s_drive[64 * B];      // [j][b], 32 KB
    __shared__ float s_v[B][65];           // padded -> conflict-free
    __shared__ float s_z[B][65];
    const int tid = threadIdx.x;

    float v = 0.0f, z = 0.0f;
    for (int t0 = 0; t0 < T; t0 += 64) {
        const int TT = (T - t0 < 64) ? (T - t0) : 64;   // 64 or 40
        const int nq = (TT * B) / 4;                    // float4 count

        // P0: coalesced tile load (drive_t tile is contiguous in [T,B])
        const f32x4* src = (const f32x4*)(drive_t + t0 * B);
        f32x4* dst = (f32x4*)s_drive;
        for (int idx = tid; idx < nq; idx += 512)
            dst[idx] = src[idx];
        __syncthreads();

        // PA: serial scan, one thread per batch row
        if (tid < B) {
            float vv = v, zz = z;
            for (int j = 0; j < TT; ++j) {
                const float d = s_drive[j * B + tid];
                vv = ALPHA * vv + d - V_TH * zz;
                zz = (vv - V_TH > 0.0f) ? 1.0f : 0.0f;
                s_v[tid][j] = vv;
                s_z[tid][j] = zz;
            }
            v = vv; z = zz;
        }
        __syncthreads();

        // PB: aligned float4 stores (TT%4==0, T%4==0, t0%4==0)
        const int qpb = TT / 4;                         // quads per row
        for (int idx = tid; idx < nq; idx += 512) {
            const int bb = idx / qpb;
            const int j4 = (idx - bb * qpb) * 4;
            f32x4 vq = { s_v[bb][j4], s_v[bb][j4+1], s_v[bb][j4+2], s_v[bb][j4+3] };
            *(f32x4*)(out + (long long)bb * T + t0 + j4) = vq;
            f32x4 zq = { s_z[bb][j4], s_z[bb][j4+1], s_z[bb][j4+2], s_z[bb][j4+3] };
            *(f32x4*)(out + (long long)(B + bb) * T + t0 + j4) = zq;
        }
        __syncthreads();   // LDS reused next tile
    }
}

extern "C" void kernel_launch(void* const* d_in, const int* in_sizes, int n_in,
                              void* d_out, int out_size, void* d_ws, size_t ws_size,
                              hipStream_t stream) {
    const float* x = (const float*)d_in[0];   // [B,T,N]
    const float* w = (const float*)d_in[1];   // [N]
    float* out = (float*)d_out;               // v[B,T] ++ z[B,T]
    float* drive_t = (float*)d_ws;            // [T,B] scratch, 512 KB

    // one wave per row: 128000 waves, 4 per block
    lif_dot_kernel<<<(B * T) / 4, 256, 0, stream>>>(x, w, drive_t);
    lif_scan_kernel<<<1, 512, 0, stream>>>(drive_t, out);
}